// Round 14
// baseline (241.318 us; speedup 1.0000x reference)
//
#include <hip/hip_runtime.h>
#include <math.h>

#define L_SEQ 4096
#define C_DIM 512
#define NH 8
#define DK 64
#define NB 2
#define QSC 0.18033688011112042f  /* (1/sqrt(64)) * log2(e) */

typedef _Float16 f16;
typedef _Float16 f16x8 __attribute__((ext_vector_type(8)));
typedef _Float16 f16x4 __attribute__((ext_vector_type(4)));
typedef __fp16 h16x2 __attribute__((ext_vector_type(2)));   // builtin ABI type
typedef float f32x4 __attribute__((ext_vector_type(4)));
typedef float f32x16 __attribute__((ext_vector_type(16)));
typedef unsigned int u32;

// ---------------------------------------------------------------------------
// prep: z=0,1 -> transpose-cast X[b] [512][4096] fp32 -> Xt [b*4096+t][512] f16
//       z=2   -> plain-cast Wq, Wkv[0:512], Wkv[512:1024], Wp -> f16
// (Wq, Wk, Wv land contiguously as Wqkv [1536][512] for the fused projection.)
// ---------------------------------------------------------------------------
__global__ __launch_bounds__(256) void prep(
    const float* __restrict__ X, const float* __restrict__ Wq,
    const float* __restrict__ Wkv, const float* __restrict__ Wp,
    f16* __restrict__ Xt, f16* __restrict__ Wqkh,
    f16* __restrict__ Wvh, f16* __restrict__ Wph)
{
    const int tid = threadIdx.x;
    const int z = blockIdx.z;
    if (z < 2) {
        __shared__ f16 Ts[64][72];
        const float* src = X + (size_t)z * C_DIM * L_SEQ;
        f16* dst = Xt + (size_t)z * L_SEQ * C_DIM;
        for (int tile = blockIdx.x; tile < 512; tile += gridDim.x) {
            const int c0 = (tile & 7) * 64;
            const int t0 = (tile >> 3) * 64;
            __syncthreads();
            #pragma unroll
            for (int p = 0; p < 4; ++p) {
                const int c = (tid >> 4) + p * 16;
                const int t = (tid & 15) * 4;
                const float4 v = *(const float4*)(src + (size_t)(c0 + c) * L_SEQ + t0 + t);
                Ts[t + 0][c] = (f16)v.x; Ts[t + 1][c] = (f16)v.y;
                Ts[t + 2][c] = (f16)v.z; Ts[t + 3][c] = (f16)v.w;
            }
            __syncthreads();
            #pragma unroll
            for (int p = 0; p < 2; ++p) {
                const int t = (tid >> 3) + p * 32;
                const int ch = (tid & 7) * 8;
                *(f16x8*)(dst + (size_t)(t0 + t) * C_DIM + c0 + ch) =
                    *(const f16x8*)&Ts[t][ch];
            }
        }
    } else {
        const float* srcs[4] = {Wq, Wkv, Wkv + 262144, Wp};
        f16* dsts[4] = {Wqkh, Wqkh + 262144, Wvh, Wph};
        #pragma unroll
        for (int s = 0; s < 4; ++s) {
            const float* sp = srcs[s]; f16* dp = dsts[s];
            for (int i = blockIdx.x * 256 + tid; i < 65536; i += gridDim.x * 256) {
                const float4 v = *(const float4*)(sp + (size_t)i * 4);
                f16x4 h; h[0] = (f16)v.x; h[1] = (f16)v.y; h[2] = (f16)v.z; h[3] = (f16)v.w;
                *(f16x4*)(dp + (size_t)i * 4) = h;
            }
        }
    }
}

// ---------------------------------------------------------------------------
// Fused Q/K/V projection, fp16 MFMA. m = tokens (8192), n = channels (1536).
// A = Xt[t][c], B = Wqkv[o][c] (Wq,Wk,Wv contiguous). C row=t, col=o.
//  o <  512: Q (bias bq, xQSC) -> Qh token-major [bh][t][64]
//  o < 1024: K (bias bkv)      -> Kh token-major
//  o >=1024: V (bias bkv[512+c]) -> Vh channel-major [bh][d][t'] with t' =
//    t bits2<->3 swapped (flash16's PV layout). In this C-layout the permuted
//    bits live in `quad`: qp = ((quad&1)<<1)|(quad>>1).
// ---------------------------------------------------------------------------
__global__ __launch_bounds__(256) void qkv_mfma(
    const f16* __restrict__ Xt, const f16* __restrict__ Wqkv,
    const float* __restrict__ bq, const float* __restrict__ bkv,
    f16* __restrict__ Qh, f16* __restrict__ Kh, f16* __restrict__ Vh)
{
    __shared__ f16 As[128][40];
    __shared__ f16 Bs[128][40];
    const int tid = threadIdx.x;
    const int lane = tid & 63, w = tid >> 6;
    const int l15 = lane & 15, quad = lane >> 4;
    const int wy = w >> 1, wx = w & 1;
    const int mb0 = blockIdx.x * 128;   // token tile
    const int n0  = blockIdx.y * 128;   // channel tile (0..1535)

    f32x4 acc[4][4] = {};
    const int row = tid >> 2, c8 = (tid & 3) * 8;
    const f16* aptr = Xt + (size_t)mb0 * 512;
    const f16* bptr = Wqkv + (size_t)n0 * 512;

    uint4 ga0 = *(const uint4*)(aptr + (size_t)row * 512 + c8);
    uint4 ga1 = *(const uint4*)(aptr + (size_t)(row + 64) * 512 + c8);
    uint4 gb0 = *(const uint4*)(bptr + (size_t)row * 512 + c8);
    uint4 gb1 = *(const uint4*)(bptr + (size_t)(row + 64) * 512 + c8);

    for (int k0 = 0; k0 < 512; k0 += 32) {
        __syncthreads();
        *(uint4*)&As[row][c8] = ga0;
        *(uint4*)&As[row + 64][c8] = ga1;
        *(uint4*)&Bs[row][c8] = gb0;
        *(uint4*)&Bs[row + 64][c8] = gb1;
        if (k0 + 32 < 512) {
            ga0 = *(const uint4*)(aptr + (size_t)row * 512 + k0 + 32 + c8);
            ga1 = *(const uint4*)(aptr + (size_t)(row + 64) * 512 + k0 + 32 + c8);
            gb0 = *(const uint4*)(bptr + (size_t)row * 512 + k0 + 32 + c8);
            gb1 = *(const uint4*)(bptr + (size_t)(row + 64) * 512 + k0 + 32 + c8);
        }
        __syncthreads();
        f16x8 af[4], bf[4];
        #pragma unroll
        for (int i = 0; i < 4; ++i)
            af[i] = *(const f16x8*)&As[wy * 64 + i * 16 + l15][quad * 8];
        #pragma unroll
        for (int n = 0; n < 4; ++n)
            bf[n] = *(const f16x8*)&Bs[wx * 64 + n * 16 + l15][quad * 8];
        #pragma unroll
        for (int i = 0; i < 4; ++i)
            #pragma unroll
            for (int n = 0; n < 4; ++n)
                acc[i][n] = __builtin_amdgcn_mfma_f32_16x16x32_f16(af[i], bf[n], acc[i][n], 0, 0, 0);
    }

    // V-path: swap bits 2,3 of t (here t&15 = quad*4 + r -> swap quad's bits)
    const int qp = ((quad & 1) << 1) | (quad >> 1);

    #pragma unroll
    for (int nn = 0; nn < 4; ++nn) {
        const int o = n0 + wx * 64 + nn * 16 + l15;
        if (o < 1024) {
            const bool isQ = (o < 512);
            const float bias = isQ ? bq[o] : bkv[o - 512];
            const int h = (o & 511) >> 6, d = o & 63;
            f16* base = isQ ? Qh : Kh;
            #pragma unroll
            for (int i = 0; i < 4; ++i) {
                const int tr = mb0 + wy * 64 + i * 16 + quad * 4;
                #pragma unroll
                for (int r = 0; r < 4; ++r) {
                    const int tg = tr + r;
                    const int bh = (tg >> 12) * NH + h;
                    float v = acc[i][nn][r] + bias;
                    if (isQ) v *= QSC;
                    base[((size_t)bh * L_SEQ + (tg & 4095)) * DK + d] = (f16)v;
                }
            }
        } else {
            const int c = o - 1024;
            const float bias = bkv[512 + c];
            const int h = c >> 6, d = c & 63;
            #pragma unroll
            for (int i = 0; i < 4; ++i) {
                const int trp = mb0 + wy * 64 + i * 16 + qp * 4;  // permuted t base
                #pragma unroll
                for (int r = 0; r < 4; ++r) {
                    const int tq = trp + r;
                    const int bh = (tq >> 12) * NH + h;
                    const float v = acc[i][nn][r] + bias;
                    Vh[((size_t)bh * DK + d) * L_SEQ + (tq & 4095)] = (f16)v;
                }
            }
        }
    }
}

// ---------------------------------------------------------------------------
// Out-projection (verbatim r11): 64-channel tiles, grid (64,8) = 2 blocks/CU.
// ---------------------------------------------------------------------------
__global__ __launch_bounds__(256) void oproj2(
    const f16* __restrict__ Bsrc, const f16* __restrict__ Wh,
    const float* __restrict__ bias, float* __restrict__ outP)
{
    __shared__ f16 As[64][40];
    __shared__ f16 Bs[128][40];
    const int tid = threadIdx.x;
    const int lane = tid & 63, w = tid >> 6;
    const int l15 = lane & 15, quad = lane >> 4;
    const int wy = w >> 1, wx = w & 1;
    const int n0  = blockIdx.x * 128;   // token tile
    const int mb0 = blockIdx.y * 64;    // channel tile

    f32x4 acc[2][4] = {};
    const int row = tid >> 2, c8 = (tid & 3) * 8;
    const f16* aptr = Wh + (size_t)mb0 * 512;
    const f16* bptr = Bsrc + (size_t)n0 * 512;

    uint4 ga0 = *(const uint4*)(aptr + (size_t)row * 512 + c8);
    uint4 gb0 = *(const uint4*)(bptr + (size_t)row * 512 + c8);
    uint4 gb1 = *(const uint4*)(bptr + (size_t)(row + 64) * 512 + c8);

    for (int k0 = 0; k0 < 512; k0 += 32) {
        __syncthreads();
        *(uint4*)&As[row][c8] = ga0;
        *(uint4*)&Bs[row][c8] = gb0;
        *(uint4*)&Bs[row + 64][c8] = gb1;
        if (k0 + 32 < 512) {
            ga0 = *(const uint4*)(aptr + (size_t)row * 512 + k0 + 32 + c8);
            gb0 = *(const uint4*)(bptr + (size_t)row * 512 + k0 + 32 + c8);
            gb1 = *(const uint4*)(bptr + (size_t)(row + 64) * 512 + k0 + 32 + c8);
        }
        __syncthreads();
        f16x8 af[2], bf[4];
        #pragma unroll
        for (int i = 0; i < 2; ++i)
            af[i] = *(const f16x8*)&As[wy * 32 + i * 16 + l15][quad * 8];
        #pragma unroll
        for (int n = 0; n < 4; ++n)
            bf[n] = *(const f16x8*)&Bs[wx * 64 + n * 16 + l15][quad * 8];
        #pragma unroll
        for (int i = 0; i < 2; ++i)
            #pragma unroll
            for (int n = 0; n < 4; ++n)
                acc[i][n] = __builtin_amdgcn_mfma_f32_16x16x32_f16(af[i], bf[n], acc[i][n], 0, 0, 0);
    }

    #pragma unroll
    for (int i = 0; i < 2; ++i) {
        #pragma unroll
        for (int r = 0; r < 4; ++r) {
            const int o = mb0 + wy * 32 + i * 16 + quad * 4 + r;   // channel
            const float bv = bias[o];
            #pragma unroll
            for (int nn = 0; nn < 4; ++nn) {
                const int tg = n0 + wx * 64 + nn * 16 + l15;
                outP[((size_t)(tg >> 12) * C_DIM + o) * L_SEQ + (tg & 4095)] =
                    acc[i][nn][r] + bv;
            }
        }
    }
}

// ---------------------------------------------------------------------------
// Flash attention v15 = v14 with K moved OUT of LDS into registers:
//  * K fragments are clean per-lane 16B global loads (content identical to
//    the old swizzled-LDS path: staging pre-swizzle ^ read swizzle cancel).
//    Double-buffered one iteration ahead in named reg sets K0/K1.
//  * All 32 t-blocks of a bh land on the same XCD (blockid = bh + 16*ty),
//    so K (512 KB/bh) is L2-resident after the first block.
//  * LDS = V only (triple-buffered, 24 KB); LDS reads halve (16 -> 8 b128
//    per wave-iter); K staging DMA and swizzle disappear.
// Full-s per block, ones-MFMA row-sum, in-kernel normalize, direct Oh.
// ---------------------------------------------------------------------------
__device__ __forceinline__ void gload_lds16(const char* g, char* l) {
    __builtin_amdgcn_global_load_lds(
        (const __attribute__((address_space(1))) void*)g,
        (__attribute__((address_space(3))) void*)l, 16, 0, 0);
}

union FR { u32 u[4]; f16x8 v; };

__device__ __forceinline__ void pack8(const f32x16& S, FR* fr, int base) {
    #pragma unroll
    for (int q = 0; q < 4; ++q) {
        const h16x2 a01 = __builtin_amdgcn_cvt_pkrtz(
            __builtin_amdgcn_exp2f(S[4 * q + 0]),
            __builtin_amdgcn_exp2f(S[4 * q + 1]));
        const h16x2 a23 = __builtin_amdgcn_cvt_pkrtz(
            __builtin_amdgcn_exp2f(S[4 * q + 2]),
            __builtin_amdgcn_exp2f(S[4 * q + 3]));
        union { h16x2 h; u32 u; } p0, p1; p0.h = a01; p1.h = a23;
        fr[base + (q >> 1)].u[(q & 1) * 2 + 0] = p0.u;
        fr[base + (q >> 1)].u[(q & 1) * 2 + 1] = p1.u;
    }
}

__global__ __launch_bounds__(256, 2) void flash16(
    const f16* __restrict__ Qh, const f16* __restrict__ Kh,
    const f16* __restrict__ Vh, f16* __restrict__ Oh)
{
    __shared__ f16 VS[3][4096];        // [buf][d][kk] (cols bank-XOR swizzled)
    const int tid = threadIdx.x;
    const int lane = tid & 63, w = tid >> 6;
    const int l31 = lane & 31, hl = lane >> 5;
    const int bh = blockIdx.x;          // XCD locality: bh % 8 picks the XCD
    const int t0 = blockIdx.y * 128;
    const int wtb = t0 + w * 32;        // this wave's 32 tokens
    const f16* Qg = Qh + (size_t)bh * L_SEQ * DK;
    const char* Kg = (const char*)(Kh + (size_t)bh * L_SEQ * DK);
    const char* Vg = (const char*)(Vh + (size_t)bh * DK * L_SEQ);

    // persistent Q B-fragments (already scaled by QSC): col=t=l31, k=d
    f16x8 qf[4];
    #pragma unroll
    for (int kst = 0; kst < 4; ++kst)
        qf[kst] = *(const f16x8*)(Qg + (size_t)(wtb + l31) * DK + kst * 16 + hl * 8);

    // V staging: 512 16B chunks per 8KB tile; thread covers chunks tid, tid+256.
    const int c0 = tid, c1 = tid + 256;
    const int vofs0 = (c0 >> 3) * 8192 + (((c0 & 7) * 16) ^ (((c0 >> 3) & 7) << 4));
    const int vofs1 = (c1 >> 3) * 8192 + (((c1 & 7) * 16) ^ (((c1 >> 3) & 7) << 4));
    const int lb0 = (w * 64) * 16, lb1 = (256 + w * 64) * 16;   // wave-uniform LDS bases

    #define STAGE_V(vOfs, s0v) do {                                  \
        const char* vg_ = Vg + (size_t)(s0v) * 2;                    \
        char* vl_ = (char*)&VS[0][0] + (vOfs);                       \
        gload_lds16(vg_ + vofs0, vl_ + lb0);                         \
        gload_lds16(vg_ + vofs1, vl_ + lb1);                         \
    } while (0)

    // per-lane K base: row s0+l31 (A-set) / s0+32+l31 (B-set), 16B at hl*16
    const char* KgL = Kg + (size_t)l31 * 128 + hl * 16;

    f32x16 O0 = {}, O1 = {};            // [d-blk]
    f32x16 Lacc = {};                   // ones-MFMA row-sum accumulator
    f16x8 onesv;
    #pragma unroll
    for (int j = 0; j < 8; ++j) onesv[j] = (f16)1.f;
    FR frA[4], frB[4];
    f16x8 k0a[4], k0b[4], k1a[4], k1b[4];   // K double buffer (registers)

    // prologue: K for tile0 -> K0; V tile0 -> VS[0]
    #pragma unroll
    for (int kst = 0; kst < 4; ++kst) {
        k0a[kst] = *(const f16x8*)(KgL + kst * 32);
        k0b[kst] = *(const f16x8*)(KgL + 32 * 128 + kst * 32);
    }
    STAGE_V(0, 0);
    __syncthreads();

    const int swz = (l31 & 7) << 4;
    const int rowA = l31 * 128, rowB = (32 + l31) * 128;

    // one iteration: prefetch K(i+1)->KN, stage V(i+1), QK-A, pack-A,
    // QK-B + PV(i-1), pack-B, L-MFMA, barrier.
    #define QKBODY(s0v, DOSTG, DOPV, stO, pvO, frC, frP, KCa, KCb, KNa, KNb) do { \
        if (DOSTG) {                                                        \
            const char* kg_ = KgL + (size_t)((s0v) + 64) * 128;             \
            _Pragma("unroll")                                               \
            for (int kst = 0; kst < 4; ++kst) {                             \
                KNa[kst] = *(const f16x8*)(kg_ + kst * 32);                 \
                KNb[kst] = *(const f16x8*)(kg_ + 32 * 128 + kst * 32);      \
            }                                                               \
            STAGE_V(stO, (s0v) + 64);                                       \
        }                                                                   \
        {                                                                   \
            f32x16 Sa = {};                                                 \
            __builtin_amdgcn_s_setprio(1);                                  \
            _Pragma("unroll")                                               \
            for (int kst = 0; kst < 4; ++kst)                               \
                Sa = __builtin_amdgcn_mfma_f32_32x32x16_f16(KCa[kst], qf[kst], Sa, 0, 0, 0); \
            __builtin_amdgcn_s_setprio(0);                                  \
            pack8(Sa, frC, 0);                                              \
        }                                                                   \
        {                                                                   \
            f32x16 Sb = {};                                                 \
            __builtin_amdgcn_s_setprio(1);                                  \
            _Pragma("unroll")                                               \
            for (int kst = 0; kst < 4; ++kst)                               \
                Sb = __builtin_amdgcn_mfma_f32_32x32x16_f16(KCb[kst], qf[kst], Sb, 0, 0, 0); \
            if (DOPV) {                                                     \
                const char* Vb = (const char*)&VS[0][0] + (pvO);            \
                _Pragma("unroll")                                           \
                for (int kst = 0; kst < 4; ++kst) {                         \
                    const int ca = (kst * 32 + hl * 16) ^ swz;              \
                    const f16x8 v0 = *(const f16x8*)(Vb + rowA + ca);       \
                    const f16x8 v1 = *(const f16x8*)(Vb + rowB + ca);       \
                    O0 = __builtin_amdgcn_mfma_f32_32x32x16_f16(v0, frP[kst].v, O0, 0, 0, 0); \
                    O1 = __builtin_amdgcn_mfma_f32_32x32x16_f16(v1, frP[kst].v, O1, 0, 0, 0); \
                }                                                           \
            }                                                               \
            __builtin_amdgcn_s_setprio(0);                                  \
            pack8(Sb, frC, 2);                                              \
            _Pragma("unroll")                                               \
            for (int kst = 0; kst < 4; ++kst)                               \
                Lacc = __builtin_amdgcn_mfma_f32_32x32x16_f16(onesv, frC[kst].v, Lacc, 0, 0, 0); \
        }                                                                   \
        __syncthreads();                                                    \
    } while (0)

    // it = 0: compute K0, prefetch K1; no PV; stages V tile1 -> VS[1]
    QKBODY(0, true, false, 8192, 0, frA, frB, k0a, k0b, k1a, k1b);

    int s0 = 64;
    int stO = 16384, pvO = 0;   // it1: stage tile2 -> VS[2]; PV(0) -> VS[0]
    #pragma unroll 1
    for (int p = 0; p < 31; ++p) {
        // odd it: compute K1, prefetch K0; cur=frB, prev=frA
        QKBODY(s0, true, true, stO, pvO, frB, frA, k1a, k1b, k0a, k0b);
        s0 += 64; stO = (stO == 16384) ? 0 : stO + 8192; pvO = (pvO == 16384) ? 0 : pvO + 8192;
        // even it: compute K0, prefetch K1; cur=frA, prev=frB
        QKBODY(s0, true, true, stO, pvO, frA, frB, k0a, k0b, k1a, k1b);
        s0 += 64; stO = (stO == 16384) ? 0 : stO + 8192; pvO = (pvO == 16384) ? 0 : pvO + 8192;
    }
    // it = 63 (odd): compute K1 (loaded in it62); no prefetch/stage;
    // PV(62) from VS[62%3=2] (pvO=16384)
    QKBODY(s0, false, true, 0, pvO, frB, frA, k1a, k1b, k0a, k0b);

    // epilogue: PV(63) -- tile63 lives in VS[63%3 = 0], fr in frB (already
    // included in Lacc at production time)
    {
        const char* Vb = (const char*)&VS[0][0];
        __builtin_amdgcn_s_setprio(1);
        #pragma unroll
        for (int kst = 0; kst < 4; ++kst) {
            const int ca = (kst * 32 + hl * 16) ^ swz;
            const f16x8 v0 = *(const f16x8*)(Vb + rowA + ca);
            const f16x8 v1 = *(const f16x8*)(Vb + rowB + ca);
            O0 = __builtin_amdgcn_mfma_f32_32x32x16_f16(v0, frB[kst].v, O0, 0, 0, 0);
            O1 = __builtin_amdgcn_mfma_f32_32x32x16_f16(v1, frB[kst].v, O1, 0, 0, 0);
        }
        __builtin_amdgcn_s_setprio(0);
    }
    #undef QKBODY
    #undef STAGE_V

    // full softmax denominator: every element of Lacc holds sum_s P[s][t]
    const float rinv = 1.f / Lacc[0];

    // normalized O -> token-major Oh[b*4096+t][h*64+d]
    // lane (l31,hl): t = wtb+l31; d = 8*run + 4*hl + j (+32 for O1)
    const int b = bh >> 3, h = bh & 7;
    f16* OhP = Oh + ((size_t)(b * L_SEQ + wtb + l31)) * C_DIM + h * DK;
    #pragma unroll
    for (int run = 0; run < 4; ++run) {
        f16x4 v0, v1;
        #pragma unroll
        for (int j = 0; j < 4; ++j) {
            v0[j] = (f16)(O0[run * 4 + j] * rinv);
            v1[j] = (f16)(O1[run * 4 + j] * rinv);
        }
        *(f16x4*)(OhP + run * 8 + 4 * hl) = v0;
        *(f16x4*)(OhP + 32 + run * 8 + 4 * hl) = v1;
    }
}

// ---------------------------------------------------------------------------
extern "C" void kernel_launch(void* const* d_in, const int* in_sizes, int n_in,
                              void* d_out, int out_size, void* d_ws, size_t ws_size,
                              hipStream_t stream) {
    (void)in_sizes; (void)n_in; (void)out_size; (void)ws_size;
    const float* x   = (const float*)d_in[0];
    const float* Wq  = (const float*)d_in[1];
    const float* bq  = (const float*)d_in[2];
    const float* Wkv = (const float*)d_in[3];
    const float* bkv = (const float*)d_in[4];
    const float* Wp  = (const float*)d_in[5];
    const float* bp  = (const float*)d_in[6];
    float* out = (float*)d_out;

    f16* Xt    = (f16*)d_ws;           // [8192][512]
    f16* Wqkh  = Xt + 4194304;         // [1536][512] fused Wq|Wk|Wv
    f16* Wvh   = Wqkh + 524288;        //   (V rows, contiguous with Wqkh)
    f16* Wph   = Wvh + 262144;         // [512][512]
    f16* Qh    = Wph + 262144;         // [16][4096][64]
    f16* Kh    = Qh + 4194304;
    f16* Vh    = Kh + 4194304;         // [16*64][4096] (token idx bit2<->3 permuted)
    f16* Oh    = Vh + 4194304;         // [8192][512]

    prep<<<dim3(128, 1, 3), 256, 0, stream>>>(x, Wq, Wkv, Wp, Xt, Wqkh, Wvh, Wph);
    qkv_mfma<<<dim3(64, 12), 256, 0, stream>>>(Xt, Wqkh, bq, bkv, Qh, Kh, Vh);
    flash16<<<dim3(16, 32), 256, 0, stream>>>(Qh, Kh, Vh, Oh);
    oproj2<<<dim3(64, 8), 256, 0, stream>>>(Oh, Wph, bp, out);
}

// Round 15
// 194.634 us; speedup vs baseline: 1.2399x; 1.2399x over previous
//
#include <hip/hip_runtime.h>
#include <math.h>

#define L_SEQ 4096
#define C_DIM 512
#define NH 8
#define DK 64
#define NB 2
#define QSC 0.18033688011112042f  /* (1/sqrt(64)) * log2(e) */

typedef _Float16 f16;
typedef _Float16 f16x8 __attribute__((ext_vector_type(8)));
typedef _Float16 f16x4 __attribute__((ext_vector_type(4)));
typedef __fp16 h16x2 __attribute__((ext_vector_type(2)));   // builtin ABI type
typedef float f32x4 __attribute__((ext_vector_type(4)));
typedef float f32x16 __attribute__((ext_vector_type(16)));
typedef unsigned int u32;

// ---------------------------------------------------------------------------
// prep: z=0,1 -> transpose-cast X[b] [512][4096] fp32 -> Xt [b*4096+t][512] f16
//       z=2   -> plain-cast Wq, Wkv[0:512], Wkv[512:1024], Wp -> f16
// (Wq, Wk, Wv land contiguously as Wqkv [1536][512] for the fused projection.)
// ---------------------------------------------------------------------------
__global__ __launch_bounds__(256) void prep(
    const float* __restrict__ X, const float* __restrict__ Wq,
    const float* __restrict__ Wkv, const float* __restrict__ Wp,
    f16* __restrict__ Xt, f16* __restrict__ Wqkh,
    f16* __restrict__ Wvh, f16* __restrict__ Wph)
{
    const int tid = threadIdx.x;
    const int z = blockIdx.z;
    if (z < 2) {
        __shared__ f16 Ts[64][72];
        const float* src = X + (size_t)z * C_DIM * L_SEQ;
        f16* dst = Xt + (size_t)z * L_SEQ * C_DIM;
        for (int tile = blockIdx.x; tile < 512; tile += gridDim.x) {
            const int c0 = (tile & 7) * 64;
            const int t0 = (tile >> 3) * 64;
            __syncthreads();
            #pragma unroll
            for (int p = 0; p < 4; ++p) {
                const int c = (tid >> 4) + p * 16;
                const int t = (tid & 15) * 4;
                const float4 v = *(const float4*)(src + (size_t)(c0 + c) * L_SEQ + t0 + t);
                Ts[t + 0][c] = (f16)v.x; Ts[t + 1][c] = (f16)v.y;
                Ts[t + 2][c] = (f16)v.z; Ts[t + 3][c] = (f16)v.w;
            }
            __syncthreads();
            #pragma unroll
            for (int p = 0; p < 2; ++p) {
                const int t = (tid >> 3) + p * 32;
                const int ch = (tid & 7) * 8;
                *(f16x8*)(dst + (size_t)(t0 + t) * C_DIM + c0 + ch) =
                    *(const f16x8*)&Ts[t][ch];
            }
        }
    } else {
        const float* srcs[4] = {Wq, Wkv, Wkv + 262144, Wp};
        f16* dsts[4] = {Wqkh, Wqkh + 262144, Wvh, Wph};
        #pragma unroll
        for (int s = 0; s < 4; ++s) {
            const float* sp = srcs[s]; f16* dp = dsts[s];
            for (int i = blockIdx.x * 256 + tid; i < 65536; i += gridDim.x * 256) {
                const float4 v = *(const float4*)(sp + (size_t)i * 4);
                f16x4 h; h[0] = (f16)v.x; h[1] = (f16)v.y; h[2] = (f16)v.z; h[3] = (f16)v.w;
                *(f16x4*)(dp + (size_t)i * 4) = h;
            }
        }
    }
}

// ---------------------------------------------------------------------------
// Fused Q/K/V projection, fp16 MFMA. m = tokens (8192), n = channels (1536).
// A = Xt[t][c], B = Wqkv[o][c] (Wq,Wk,Wv contiguous). C row=t, col=o.
//  o <  512: Q (bias bq, xQSC) -> Qh token-major [bh][t][64]
//  o < 1024: K (bias bkv)      -> Kh token-major
//  o >=1024: V (bias bkv[512+c]) -> Vh channel-major [bh][d][t'] with t' =
//    t bits2<->3 swapped (flash16's PV layout). In this C-layout the permuted
//    bits live in `quad`: qp = ((quad&1)<<1)|(quad>>1).
// ---------------------------------------------------------------------------
__global__ __launch_bounds__(256) void qkv_mfma(
    const f16* __restrict__ Xt, const f16* __restrict__ Wqkv,
    const float* __restrict__ bq, const float* __restrict__ bkv,
    f16* __restrict__ Qh, f16* __restrict__ Kh, f16* __restrict__ Vh)
{
    __shared__ f16 As[128][40];
    __shared__ f16 Bs[128][40];
    const int tid = threadIdx.x;
    const int lane = tid & 63, w = tid >> 6;
    const int l15 = lane & 15, quad = lane >> 4;
    const int wy = w >> 1, wx = w & 1;
    const int mb0 = blockIdx.x * 128;   // token tile
    const int n0  = blockIdx.y * 128;   // channel tile (0..1535)

    f32x4 acc[4][4] = {};
    const int row = tid >> 2, c8 = (tid & 3) * 8;
    const f16* aptr = Xt + (size_t)mb0 * 512;
    const f16* bptr = Wqkv + (size_t)n0 * 512;

    uint4 ga0 = *(const uint4*)(aptr + (size_t)row * 512 + c8);
    uint4 ga1 = *(const uint4*)(aptr + (size_t)(row + 64) * 512 + c8);
    uint4 gb0 = *(const uint4*)(bptr + (size_t)row * 512 + c8);
    uint4 gb1 = *(const uint4*)(bptr + (size_t)(row + 64) * 512 + c8);

    for (int k0 = 0; k0 < 512; k0 += 32) {
        __syncthreads();
        *(uint4*)&As[row][c8] = ga0;
        *(uint4*)&As[row + 64][c8] = ga1;
        *(uint4*)&Bs[row][c8] = gb0;
        *(uint4*)&Bs[row + 64][c8] = gb1;
        if (k0 + 32 < 512) {
            ga0 = *(const uint4*)(aptr + (size_t)row * 512 + k0 + 32 + c8);
            ga1 = *(const uint4*)(aptr + (size_t)(row + 64) * 512 + k0 + 32 + c8);
            gb0 = *(const uint4*)(bptr + (size_t)row * 512 + k0 + 32 + c8);
            gb1 = *(const uint4*)(bptr + (size_t)(row + 64) * 512 + k0 + 32 + c8);
        }
        __syncthreads();
        f16x8 af[4], bf[4];
        #pragma unroll
        for (int i = 0; i < 4; ++i)
            af[i] = *(const f16x8*)&As[wy * 64 + i * 16 + l15][quad * 8];
        #pragma unroll
        for (int n = 0; n < 4; ++n)
            bf[n] = *(const f16x8*)&Bs[wx * 64 + n * 16 + l15][quad * 8];
        #pragma unroll
        for (int i = 0; i < 4; ++i)
            #pragma unroll
            for (int n = 0; n < 4; ++n)
                acc[i][n] = __builtin_amdgcn_mfma_f32_16x16x32_f16(af[i], bf[n], acc[i][n], 0, 0, 0);
    }

    // V-path: swap bits 2,3 of t (here t&15 = quad*4 + r -> swap quad's bits)
    const int qp = ((quad & 1) << 1) | (quad >> 1);

    #pragma unroll
    for (int nn = 0; nn < 4; ++nn) {
        const int o = n0 + wx * 64 + nn * 16 + l15;
        if (o < 1024) {
            const bool isQ = (o < 512);
            const float bias = isQ ? bq[o] : bkv[o - 512];
            const int h = (o & 511) >> 6, d = o & 63;
            f16* base = isQ ? Qh : Kh;
            #pragma unroll
            for (int i = 0; i < 4; ++i) {
                const int tr = mb0 + wy * 64 + i * 16 + quad * 4;
                #pragma unroll
                for (int r = 0; r < 4; ++r) {
                    const int tg = tr + r;
                    const int bh = (tg >> 12) * NH + h;
                    float v = acc[i][nn][r] + bias;
                    if (isQ) v *= QSC;
                    base[((size_t)bh * L_SEQ + (tg & 4095)) * DK + d] = (f16)v;
                }
            }
        } else {
            const int c = o - 1024;
            const float bias = bkv[512 + c];
            const int h = c >> 6, d = c & 63;
            #pragma unroll
            for (int i = 0; i < 4; ++i) {
                const int trp = mb0 + wy * 64 + i * 16 + qp * 4;  // permuted t base
                #pragma unroll
                for (int r = 0; r < 4; ++r) {
                    const int tq = trp + r;
                    const int bh = (tq >> 12) * NH + h;
                    const float v = acc[i][nn][r] + bias;
                    Vh[((size_t)bh * DK + d) * L_SEQ + (tq & 4095)] = (f16)v;
                }
            }
        }
    }
}

// ---------------------------------------------------------------------------
// Out-projection (verbatim r11): 64-channel tiles, grid (64,8) = 2 blocks/CU.
// ---------------------------------------------------------------------------
__global__ __launch_bounds__(256) void oproj2(
    const f16* __restrict__ Bsrc, const f16* __restrict__ Wh,
    const float* __restrict__ bias, float* __restrict__ outP)
{
    __shared__ f16 As[64][40];
    __shared__ f16 Bs[128][40];
    const int tid = threadIdx.x;
    const int lane = tid & 63, w = tid >> 6;
    const int l15 = lane & 15, quad = lane >> 4;
    const int wy = w >> 1, wx = w & 1;
    const int n0  = blockIdx.x * 128;   // token tile
    const int mb0 = blockIdx.y * 64;    // channel tile

    f32x4 acc[2][4] = {};
    const int row = tid >> 2, c8 = (tid & 3) * 8;
    const f16* aptr = Wh + (size_t)mb0 * 512;
    const f16* bptr = Bsrc + (size_t)n0 * 512;

    uint4 ga0 = *(const uint4*)(aptr + (size_t)row * 512 + c8);
    uint4 gb0 = *(const uint4*)(bptr + (size_t)row * 512 + c8);
    uint4 gb1 = *(const uint4*)(bptr + (size_t)(row + 64) * 512 + c8);

    for (int k0 = 0; k0 < 512; k0 += 32) {
        __syncthreads();
        *(uint4*)&As[row][c8] = ga0;
        *(uint4*)&Bs[row][c8] = gb0;
        *(uint4*)&Bs[row + 64][c8] = gb1;
        if (k0 + 32 < 512) {
            ga0 = *(const uint4*)(aptr + (size_t)row * 512 + k0 + 32 + c8);
            gb0 = *(const uint4*)(bptr + (size_t)row * 512 + k0 + 32 + c8);
            gb1 = *(const uint4*)(bptr + (size_t)(row + 64) * 512 + k0 + 32 + c8);
        }
        __syncthreads();
        f16x8 af[2], bf[4];
        #pragma unroll
        for (int i = 0; i < 2; ++i)
            af[i] = *(const f16x8*)&As[wy * 32 + i * 16 + l15][quad * 8];
        #pragma unroll
        for (int n = 0; n < 4; ++n)
            bf[n] = *(const f16x8*)&Bs[wx * 64 + n * 16 + l15][quad * 8];
        #pragma unroll
        for (int i = 0; i < 2; ++i)
            #pragma unroll
            for (int n = 0; n < 4; ++n)
                acc[i][n] = __builtin_amdgcn_mfma_f32_16x16x32_f16(af[i], bf[n], acc[i][n], 0, 0, 0);
    }

    #pragma unroll
    for (int i = 0; i < 2; ++i) {
        #pragma unroll
        for (int r = 0; r < 4; ++r) {
            const int o = mb0 + wy * 32 + i * 16 + quad * 4 + r;   // channel
            const float bv = bias[o];
            #pragma unroll
            for (int nn = 0; nn < 4; ++nn) {
                const int tg = n0 + wx * 64 + nn * 16 + l15;
                outP[((size_t)(tg >> 12) * C_DIM + o) * L_SEQ + (tg & 4095)] =
                    acc[i][nn][r] + bv;
            }
        }
    }
}

// ---------------------------------------------------------------------------
// Flash attention v14 (revert of v15's K-gather regression; best measured):
//  * K and V both staged HBM->LDS via global_load_lds (coalesced DMA); K
//    double-buffered, V triple-buffered; b128-only XOR-swizzled LDS reads.
//  * PV deferred one tile (fr in regs); no sched_barrier; ones-MFMA row-sum
//    (Lacc = mfma(ones, fr)) replaces the serial fdot2 chain.
//  * Full-s per block, in-kernel normalize, direct token-major Oh output.
// v15 lesson: per-lane K-from-global is a 64-line strided gather -- VMEM
// issue-bound, 85.9 -> 142.8 us. LDS staging IS the coalescing mechanism.
// ---------------------------------------------------------------------------
__device__ __forceinline__ void gload_lds16(const char* g, char* l) {
    __builtin_amdgcn_global_load_lds(
        (const __attribute__((address_space(1))) void*)g,
        (__attribute__((address_space(3))) void*)l, 16, 0, 0);
}

union FR { u32 u[4]; f16x8 v; };

__device__ __forceinline__ void pack8(const f32x16& S, FR* fr, int base) {
    #pragma unroll
    for (int q = 0; q < 4; ++q) {
        const h16x2 a01 = __builtin_amdgcn_cvt_pkrtz(
            __builtin_amdgcn_exp2f(S[4 * q + 0]),
            __builtin_amdgcn_exp2f(S[4 * q + 1]));
        const h16x2 a23 = __builtin_amdgcn_cvt_pkrtz(
            __builtin_amdgcn_exp2f(S[4 * q + 2]),
            __builtin_amdgcn_exp2f(S[4 * q + 3]));
        union { h16x2 h; u32 u; } p0, p1; p0.h = a01; p1.h = a23;
        fr[base + (q >> 1)].u[(q & 1) * 2 + 0] = p0.u;
        fr[base + (q >> 1)].u[(q & 1) * 2 + 1] = p1.u;
    }
}

__global__ __launch_bounds__(256, 2) void flash16(
    const f16* __restrict__ Qh, const f16* __restrict__ Kh,
    const f16* __restrict__ Vh, f16* __restrict__ Oh)
{
    __shared__ f16 KS[2][4096];        // [buf][s][d]  (cols bank-XOR swizzled)
    __shared__ f16 VS[3][4096];        // [buf][d][kk] (cols bank-XOR swizzled)
    const int tid = threadIdx.x;
    const int lane = tid & 63, w = tid >> 6;
    const int l31 = lane & 31, hl = lane >> 5;
    const int bh = blockIdx.x;          // XCD locality: bh % 8 picks the XCD
    const int t0 = blockIdx.y * 128;
    const int wtb = t0 + w * 32;        // this wave's 32 tokens
    const f16* Qg = Qh + (size_t)bh * L_SEQ * DK;
    const char* Kg = (const char*)(Kh + (size_t)bh * L_SEQ * DK);
    const char* Vg = (const char*)(Vh + (size_t)bh * DK * L_SEQ);

    // persistent Q B-fragments (already scaled by QSC): col=t=l31, k=d
    f16x8 qf[4];
    #pragma unroll
    for (int kst = 0; kst < 4; ++kst)
        qf[kst] = *(const f16x8*)(Qg + (size_t)(wtb + l31) * DK + kst * 16 + hl * 8);

    // staging: 512 16B chunks per 8KB tile; thread covers chunks tid, tid+256.
    const int c0 = tid, c1 = tid + 256;
    const int kofs0 = (c0 >> 3) * 128  + (((c0 & 7) * 16) ^ (((c0 >> 3) & 7) << 4));
    const int kofs1 = (c1 >> 3) * 128  + (((c1 & 7) * 16) ^ (((c1 >> 3) & 7) << 4));
    const int vofs0 = (c0 >> 3) * 8192 + (((c0 & 7) * 16) ^ (((c0 >> 3) & 7) << 4));
    const int vofs1 = (c1 >> 3) * 8192 + (((c1 & 7) * 16) ^ (((c1 >> 3) & 7) << 4));
    const int lb0 = (w * 64) * 16, lb1 = (256 + w * 64) * 16;   // wave-uniform LDS bases

    #define STAGE_K(kb, s0v) do {                                    \
        const char* kg_ = Kg + (size_t)(s0v) * 128;                  \
        char* kl_ = (char*)&KS[kb][0];                               \
        gload_lds16(kg_ + kofs0, kl_ + lb0);                         \
        gload_lds16(kg_ + kofs1, kl_ + lb1);                         \
    } while (0)
    #define STAGE_V(vOfs, s0v) do {                                  \
        const char* vg_ = Vg + (size_t)(s0v) * 2;                    \
        char* vl_ = (char*)&VS[0][0] + (vOfs);                       \
        gload_lds16(vg_ + vofs0, vl_ + lb0);                         \
        gload_lds16(vg_ + vofs1, vl_ + lb1);                         \
    } while (0)

    f32x16 O0 = {}, O1 = {};            // [d-blk]
    f32x16 Lacc = {};                   // ones-MFMA row-sum accumulator
    f16x8 onesv;
    #pragma unroll
    for (int j = 0; j < 8; ++j) onesv[j] = (f16)1.f;
    FR frA[4], frB[4];

    STAGE_K(0, 0); STAGE_V(0, 0);
    __syncthreads();

    const int swz = (l31 & 7) << 4;
    const int rowA = l31 * 128, rowB = (32 + l31) * 128;

    // one iteration: stage(i+1), QK-A, pack-A, QK-B + PV(i-1), pack-B, L-sum
    #define QKBODY(s0v, kbR, kbS, DOSTG, DOPV, stO, pvO, frC, frP) do {     \
        if (DOSTG) { STAGE_K(kbS, (s0v) + 64); STAGE_V(stO, (s0v) + 64); }  \
        const char* Kb = (const char*)&KS[kbR][0];                          \
        f16x8 kf[4];                                                        \
        _Pragma("unroll")                                                   \
        for (int kst = 0; kst < 4; ++kst)                                   \
            kf[kst] = *(const f16x8*)(Kb + rowA + ((kst * 32 + hl * 16) ^ swz)); \
        {                                                                   \
            f32x16 Sa = {};                                                 \
            __builtin_amdgcn_s_setprio(1);                                  \
            _Pragma("unroll")                                               \
            for (int kst = 0; kst < 4; ++kst)                               \
                Sa = __builtin_amdgcn_mfma_f32_32x32x16_f16(kf[kst], qf[kst], Sa, 0, 0, 0); \
            __builtin_amdgcn_s_setprio(0);                                  \
            _Pragma("unroll")                                               \
            for (int kst = 0; kst < 4; ++kst)                               \
                kf[kst] = *(const f16x8*)(Kb + rowB + ((kst * 32 + hl * 16) ^ swz)); \
            pack8(Sa, frC, 0);                                              \
        }                                                                   \
        {                                                                   \
            f32x16 Sb = {};                                                 \
            __builtin_amdgcn_s_setprio(1);                                  \
            _Pragma("unroll")                                               \
            for (int kst = 0; kst < 4; ++kst)                               \
                Sb = __builtin_amdgcn_mfma_f32_32x32x16_f16(kf[kst], qf[kst], Sb, 0, 0, 0); \
            if (DOPV) {                                                     \
                const char* Vb = (const char*)&VS[0][0] + (pvO);            \
                _Pragma("unroll")                                           \
                for (int kst = 0; kst < 4; ++kst) {                         \
                    const int ca = (kst * 32 + hl * 16) ^ swz;              \
                    const f16x8 v0 = *(const f16x8*)(Vb + rowA + ca);       \
                    const f16x8 v1 = *(const f16x8*)(Vb + rowB + ca);       \
                    O0 = __builtin_amdgcn_mfma_f32_32x32x16_f16(v0, frP[kst].v, O0, 0, 0, 0); \
                    O1 = __builtin_amdgcn_mfma_f32_32x32x16_f16(v1, frP[kst].v, O1, 0, 0, 0); \
                }                                                           \
            }                                                               \
            __builtin_amdgcn_s_setprio(0);                                  \
            pack8(Sb, frC, 2);                                              \
            _Pragma("unroll")                                               \
            for (int kst = 0; kst < 4; ++kst)                               \
                Lacc = __builtin_amdgcn_mfma_f32_32x32x16_f16(onesv, frC[kst].v, Lacc, 0, 0, 0); \
        }                                                                   \
        __syncthreads();                                                    \
    } while (0)

    // it = 0: cur fr = A, no PV; stages tile1 -> KS[1], VS[1]
    QKBODY(0, 0, 1, true, false, 8192, 0, frA, frB);

    int s0 = 64;
    int stO = 16384, pvO = 0;   // it1: stage tile2 -> VS[2]; PV(0) -> VS[0]
    #pragma unroll 1
    for (int p = 0; p < 31; ++p) {
        // odd it: read KS[1], stage KS[0]; cur=frB, prev=frA
        QKBODY(s0, 1, 0, true, true, stO, pvO, frB, frA);
        s0 += 64; stO = (stO == 16384) ? 0 : stO + 8192; pvO = (pvO == 16384) ? 0 : pvO + 8192;
        // even it: read KS[0], stage KS[1]; cur=frA, prev=frB
        QKBODY(s0, 0, 1, true, true, stO, pvO, frA, frB);
        s0 += 64; stO = (stO == 16384) ? 0 : stO + 8192; pvO = (pvO == 16384) ? 0 : pvO + 8192;
    }
    // it = 63 (odd): last tile, no stage; PV(62) from VS[62%3=2] (pvO=16384)
    QKBODY(s0, 1, 0, false, true, 0, pvO, frB, frA);

    // epilogue: PV(63) -- tile63 lives in VS[63%3 = 0], fr in frB (already
    // included in Lacc at production time)
    {
        const char* Vb = (const char*)&VS[0][0];
        __builtin_amdgcn_s_setprio(1);
        #pragma unroll
        for (int kst = 0; kst < 4; ++kst) {
            const int ca = (kst * 32 + hl * 16) ^ swz;
            const f16x8 v0 = *(const f16x8*)(Vb + rowA + ca);
            const f16x8 v1 = *(const f16x8*)(Vb + rowB + ca);
            O0 = __builtin_amdgcn_mfma_f32_32x32x16_f16(v0, frB[kst].v, O0, 0, 0, 0);
            O1 = __builtin_amdgcn_mfma_f32_32x32x16_f16(v1, frB[kst].v, O1, 0, 0, 0);
        }
        __builtin_amdgcn_s_setprio(0);
    }
    #undef QKBODY
    #undef STAGE_K
    #undef STAGE_V

    // full softmax denominator: every element of Lacc holds sum_s P[s][t]
    const float rinv = 1.f / Lacc[0];

    // normalized O -> token-major Oh[b*4096+t][h*64+d]
    // lane (l31,hl): t = wtb+l31; d = 8*run + 4*hl + j (+32 for O1)
    const int b = bh >> 3, h = bh & 7;
    f16* OhP = Oh + ((size_t)(b * L_SEQ + wtb + l31)) * C_DIM + h * DK;
    #pragma unroll
    for (int run = 0; run < 4; ++run) {
        f16x4 v0, v1;
        #pragma unroll
        for (int j = 0; j < 4; ++j) {
            v0[j] = (f16)(O0[run * 4 + j] * rinv);
            v1[j] = (f16)(O1[run * 4 + j] * rinv);
        }
        *(f16x4*)(OhP + run * 8 + 4 * hl) = v0;
        *(f16x4*)(OhP + 32 + run * 8 + 4 * hl) = v1;
    }
}

// ---------------------------------------------------------------------------
extern "C" void kernel_launch(void* const* d_in, const int* in_sizes, int n_in,
                              void* d_out, int out_size, void* d_ws, size_t ws_size,
                              hipStream_t stream) {
    (void)in_sizes; (void)n_in; (void)out_size; (void)ws_size;
    const float* x   = (const float*)d_in[0];
    const float* Wq  = (const float*)d_in[1];
    const float* bq  = (const float*)d_in[2];
    const float* Wkv = (const float*)d_in[3];
    const float* bkv = (const float*)d_in[4];
    const float* Wp  = (const float*)d_in[5];
    const float* bp  = (const float*)d_in[6];
    float* out = (float*)d_out;

    f16* Xt    = (f16*)d_ws;           // [8192][512]
    f16* Wqkh  = Xt + 4194304;         // [1536][512] fused Wq|Wk|Wv
    f16* Wvh   = Wqkh + 524288;        //   (V rows, contiguous with Wqkh)
    f16* Wph   = Wvh + 262144;         // [512][512]
    f16* Qh    = Wph + 262144;         // [16][4096][64]
    f16* Kh    = Qh + 4194304;
    f16* Vh    = Kh + 4194304;         // [16*64][4096] (token idx bit2<->3 permuted)
    f16* Oh    = Vh + 4194304;         // [8192][512]

    prep<<<dim3(128, 1, 3), 256, 0, stream>>>(x, Wq, Wkv, Wp, Xt, Wqkh, Wvh, Wph);
    qkv_mfma<<<dim3(64, 12), 256, 0, stream>>>(Xt, Wqkh, bq, bkv, Qh, Kh, Vh);
    flash16<<<dim3(16, 32), 256, 0, stream>>>(Qh, Kh, Vh, Oh);
    oproj2<<<dim3(64, 8), 256, 0, stream>>>(Oh, Wph, bp, out);
}